// Round 5
// baseline (2872.633 us; speedup 1.0000x reference)
//
#include <hip/hip_runtime.h>

#define EPS 1e-5f

// ---------------------------------------------------------------------------
// fill output mask with -100
// ---------------------------------------------------------------------------
__global__ void fill_kernel(float* __restrict__ out, int n, float v) {
    int i = blockIdx.x * blockDim.x + threadIdx.x;
    if (i < n) out[i] = v;
}

__global__ void zero8_kernel(float* __restrict__ a) {
    if (threadIdx.x < 8) a[threadIdx.x] = 0.f;
}

// ---------------------------------------------------------------------------
// GroupNorm(1) reduction: sum & sumsq over the (c, h, w) crop -> accs[2*batch]
// float4 fast path (crop widths/offsets are all multiples of 4 in practice),
// block-level LDS reduction -> one atomicAdd pair per block.
// ---------------------------------------------------------------------------
__global__ void gn_reduce_kernel(const float* __restrict__ in, long long inBatchStride,
                                 int inPitch, long long inPlane, int useOrig,
                                 int c, int shift, const int* __restrict__ bboxes,
                                 int batch0, float* __restrict__ accs)
{
    int batch = batch0 + blockIdx.z;
    const int* bb = bboxes + 4 * batch;
    int l = bb[0], t = bb[1], r = bb[2], btm = bb[3];
    int h = (btm - t) << shift;
    int w = (r   - l) << shift;
    int oy = useOrig ? t : 0;   // only used at stage 0 (shift==0)
    int ox = useOrig ? l : 0;
    const float* base = in + (long long)blockIdx.z * inBatchStride;

    float s = 0.f, s2 = 0.f;
    int stride = gridDim.x * blockDim.x;

    if (((w | ox | inPitch) & 3) == 0) {
        // vectorized: every row segment is 16B aligned
        int w4 = w >> 2;
        int count4 = c * h * w4;
        for (int idx = blockIdx.x * blockDim.x + threadIdx.x; idx < count4; idx += stride) {
            int xw   = idx % w4;
            int rest = idx / w4;
            int y    = rest % h;
            int ch   = rest / h;
            const float4 v = *reinterpret_cast<const float4*>(
                base + (long long)ch * inPlane + (long long)(y + oy) * inPitch + (ox + 4 * xw));
            s  += (v.x + v.y) + (v.z + v.w);
            s2 += (v.x * v.x + v.y * v.y) + (v.z * v.z + v.w * v.w);
        }
    } else {
        int count = c * h * w;
        for (int idx = blockIdx.x * blockDim.x + threadIdx.x; idx < count; idx += stride) {
            int xw   = idx % w;
            int rest = idx / w;
            int y    = rest % h;
            int ch   = rest / h;
            float v = base[(long long)ch * inPlane + (long long)(y + oy) * inPitch + (xw + ox)];
            s  += v;
            s2 += v * v;
        }
    }

    // wave64 reduction
    for (int off = 32; off > 0; off >>= 1) {
        s  += __shfl_down(s, off);
        s2 += __shfl_down(s2, off);
    }
    // block reduction (4 waves) -> single atomic pair
    __shared__ float red[2][4];
    int wid = threadIdx.x >> 6;
    if ((threadIdx.x & 63) == 0) { red[0][wid] = s; red[1][wid] = s2; }
    __syncthreads();
    if (threadIdx.x == 0) {
        float ts = (red[0][0] + red[0][1]) + (red[0][2] + red[0][3]);
        float t2 = (red[1][0] + red[1][1]) + (red[1][2] + red[1][3]);
        atomicAdd(&accs[2 * batch],     ts);
        atomicAdd(&accs[2 * batch + 1], t2);
    }
}

// ---------------------------------------------------------------------------
// normalize (affine folded) + bicubic 2x (both axes, 16 taps) + add em crop
// writes bufB (c, 2h, 2w) with pitch outPitch
// ---------------------------------------------------------------------------
__global__ void normup_kernel(const float* __restrict__ in, long long inBatchStride,
                              int inPitch, long long inPlane, int useOrig,
                              const float* __restrict__ em, long long emBatchStride, int emPitch,
                              const float* __restrict__ gw, const float* __restrict__ gb,
                              const float* __restrict__ accs,
                              float* __restrict__ outB, long long outBatchStride, int outPitch,
                              int c, int shift, const int* __restrict__ bboxes,
                              int batch0, int tilesY)
{
    int batch = batch0 + blockIdx.z;
    const int* bb = bboxes + 4 * batch;
    int l = bb[0], t = bb[1], r = bb[2], btm = bb[3];
    int h = (btm - t) << shift;
    int w = (r   - l) << shift;
    int H2 = 2 * h, W2 = 2 * w;

    int ch = blockIdx.y / tilesY;
    int ty = blockIdx.y % tilesY;
    int y2 = ty * 16 + threadIdx.y;
    int x2 = blockIdx.x * 16 + threadIdx.x;
    if (y2 >= H2 || x2 >= W2) return;

    float count = (float)(c * h * w);
    float m  = accs[2 * batch] / count;
    float var = accs[2 * batch + 1] / count - m * m;
    float rs = rsqrtf(fmaxf(var, 0.f) + EPS);
    float alpha = rs * gw[ch];
    float beta  = gb[ch] - m * alpha;

    int oy = useOrig ? t : 0;
    int ox = useOrig ? l : 0;
    const float* base = in + (long long)blockIdx.z * inBatchStride + (long long)ch * inPlane;

    const float Wv[2][4] = {
        {-0.03515625f, 0.26171875f, 0.87890625f, -0.10546875f},   // even (W75)
        {-0.10546875f, 0.87890625f, 0.26171875f, -0.03515625f}};  // odd  (W25)

    int iy = y2 >> 1, py = y2 & 1;
    int ix = x2 >> 1, px = x2 & 1;
    int by = iy - 2 + py;
    int bx = ix - 2 + px;

    float acc = 0.f;
    #pragma unroll
    for (int a = 0; a < 4; a++) {
        int ry = by + a;
        ry = ry < 0 ? 0 : (ry > h - 1 ? h - 1 : ry);
        const float* rowp = base + (long long)(ry + oy) * inPitch + ox;
        float rsum = 0.f;
        #pragma unroll
        for (int q = 0; q < 4; q++) {
            int rx = bx + q;
            rx = rx < 0 ? 0 : (rx > w - 1 ? w - 1 : rx);
            rsum += Wv[px][q] * rowp[rx];
        }
        acc += Wv[py][a] * rsum;
    }

    float val = alpha * acc + beta;
    int S = 2 << shift;  // 2^(j+1)
    val += em[(long long)blockIdx.z * emBatchStride + (long long)ch * emPitch * emPitch
              + (long long)(t * S + y2) * emPitch + (l * S + x2)];

    outB[(long long)blockIdx.z * outBatchStride + (long long)ch * outPitch * outPitch
         + (long long)y2 * outPitch + x2] = val;
}

// ---------------------------------------------------------------------------
// conv3x3 (zero pad) + bias (+ silu), COT output channels per thread.
// Block = 16x16 spatial tile; oc-group from blockIdx.y; input tile staged in
// LDS in chunks of CICH planes.
// Weights are ALSO staged in LDS per chunk and read via uniform-address
// ds_read (broadcast, conflict-free). The previous version read weights
// through block-uniform global pointers -> s_load_dword* -> scalar-cache
// thrash (stage-0 weight set 589 KB vs ~16 KB sK$) -> 12% VALUBusy.
// ---------------------------------------------------------------------------
#define CICH 4

template<int COT>
__global__ void __launch_bounds__(256)
conv_reg_kernel(const float* __restrict__ inB, long long inBatchStride, int inPitch,
                const float* __restrict__ wts, const float* __restrict__ bias,
                int cin, int doSilu,
                float* __restrict__ out, long long outBatchStride, int outPitch,
                int toMask, int shift, const int* __restrict__ bboxes,
                int batch0, int tilesY)
{
    int batch = batch0 + blockIdx.z;
    const int* bb = bboxes + 4 * batch;
    int l = bb[0], t = bb[1], r = bb[2], btm = bb[3];
    int h = (btm - t) << shift;
    int w = (r   - l) << shift;
    int H2 = 2 * h, W2 = 2 * w;

    int og = blockIdx.y / tilesY;
    int ty = blockIdx.y % tilesY;
    int oc0 = og * COT;
    int y0 = ty * 16;
    int x0 = blockIdx.x * 16;
    if (y0 >= H2 || x0 >= W2) return;  // uniform over block

    int ly = threadIdx.y, lx = threadIdx.x;
    int oy2 = y0 + ly, ox2 = x0 + lx;
    bool act = (oy2 < H2) && (ox2 < W2);
    int tid = ly * 16 + lx;

    // padded row stride 20 to break bank-conflict strides
    __shared__ float tile[CICH][18][20];
    // per-chunk weights; slot padded to 12 floats so each 9-weight row is
    // two aligned float4 + one float
    __shared__ __align__(16) float wsh[COT][CICH][12];

    const float* base = inB + (long long)blockIdx.z * inBatchStride;
    long long plane = (long long)inPitch * inPitch;

    float acc[COT];
    #pragma unroll
    for (int o = 0; o < COT; o++) acc[o] = 0.f;

    for (int ci0 = 0; ci0 < cin; ci0 += CICH) {
        // stage CICH input planes (18x18 halo tile each) into LDS
        for (int q = tid; q < CICH * 324; q += 256) {
            int p   = q / 324;
            int rem = q - p * 324;
            int yy  = rem / 18;
            int xx  = rem - yy * 18;
            int gy = y0 - 1 + yy, gx = x0 - 1 + xx;
            float v = (gy >= 0 && gy < H2 && gx >= 0 && gx < W2)
                          ? base[(long long)(ci0 + p) * plane + (long long)gy * inPitch + gx]
                          : 0.f;
            tile[p][yy][xx] = v;
        }
        // stage this chunk's weights (COT*CICH*9 <= 576 floats, coalesced)
        for (int q = tid; q < COT * CICH * 9; q += 256) {
            int o   = q / (CICH * 9);
            int rem = q - o * (CICH * 9);
            int p   = rem / 9;
            int k   = rem - p * 9;
            wsh[o][p][k] = wts[((long long)(oc0 + o) * cin + (ci0 + p)) * 9 + k];
        }
        __syncthreads();

        #pragma unroll
        for (int p = 0; p < CICH; p++) {
            float v00 = tile[p][ly    ][lx], v01 = tile[p][ly    ][lx + 1], v02 = tile[p][ly    ][lx + 2];
            float v10 = tile[p][ly + 1][lx], v11 = tile[p][ly + 1][lx + 1], v12 = tile[p][ly + 1][lx + 2];
            float v20 = tile[p][ly + 2][lx], v21 = tile[p][ly + 2][lx + 1], v22 = tile[p][ly + 2][lx + 2];

            #pragma unroll
            for (int o = 0; o < COT; o++) {
                const float4 wA = *reinterpret_cast<const float4*>(&wsh[o][p][0]);
                const float4 wB = *reinterpret_cast<const float4*>(&wsh[o][p][4]);
                const float  w8 = wsh[o][p][8];
                acc[o] += wA.x * v00 + wA.y * v01 + wA.z * v02
                        + wA.w * v10 + wB.x * v11 + wB.y * v12
                        + wB.z * v20 + wB.w * v21 + w8   * v22;
            }
        }
        __syncthreads();
    }

    if (!act) return;

    #pragma unroll
    for (int o = 0; o < COT; o++) {
        float v = acc[o] + bias[oc0 + o];
        if (doSilu) v = v / (1.f + __expf(-v));
        if (toMask) {
            int S = 2 << shift;   // 16 at stage 3
            out[(long long)batch * 1024 * 1024 + (long long)(t * S + oy2) * 1024 + (l * S + ox2)] = v;
        } else {
            out[(long long)blockIdx.z * outBatchStride + (long long)(oc0 + o) * outPitch * outPitch
                + (long long)oy2 * outPitch + ox2] = v;
        }
    }
}

// ---------------------------------------------------------------------------
static inline void launch_conv(int co, int tiles, int nz, const float* inB, long long inBS, int inPitch,
                               const float* wts, const float* bias, int cin, int doSilu,
                               float* out, long long outBS, int outPitch,
                               int toMask, int shift, const int* bboxes, int batch0,
                               hipStream_t stream)
{
    dim3 blk(16, 16);
    if (co == 64) {       // 4 groups of 16
        conv_reg_kernel<16><<<dim3(tiles, tiles * 4, nz), blk, 0, stream>>>(
            inB, inBS, inPitch, wts, bias, cin, doSilu, out, outBS, outPitch,
            toMask, shift, bboxes, batch0, tiles);
    } else if (co == 16) {
        conv_reg_kernel<16><<<dim3(tiles, tiles, nz), blk, 0, stream>>>(
            inB, inBS, inPitch, wts, bias, cin, doSilu, out, outBS, outPitch,
            toMask, shift, bboxes, batch0, tiles);
    } else if (co == 4) {
        conv_reg_kernel<4><<<dim3(tiles, tiles, nz), blk, 0, stream>>>(
            inB, inBS, inPitch, wts, bias, cin, doSilu, out, outBS, outPitch,
            toMask, shift, bboxes, batch0, tiles);
    } else {
        conv_reg_kernel<1><<<dim3(tiles, tiles, nz), blk, 0, stream>>>(
            inB, inBS, inPitch, wts, bias, cin, doSilu, out, outBS, outPitch,
            toMask, shift, bboxes, batch0, tiles);
    }
}

extern "C" void kernel_launch(void* const* d_in, const int* in_sizes, int n_in,
                              void* d_out, int out_size, void* d_ws, size_t ws_size,
                              hipStream_t stream)
{
    const float* x  = (const float*)d_in[0];
    const float* em[4];
    const float* gw[4];
    const float* gb[4];
    const float* cw[4];
    const float* cb[4];
    for (int j = 0; j < 4; j++) {
        em[j] = (const float*)d_in[1 + j];
        gw[j] = (const float*)d_in[5 + 4 * j];
        gb[j] = (const float*)d_in[6 + 4 * j];
        cw[j] = (const float*)d_in[7 + 4 * j];
        cb[j] = (const float*)d_in[8 + 4 * j];
    }
    const int* bboxes = (const int*)d_in[21];
    float* out = (float*)d_out;
    float* ws  = (float*)d_ws;

    const int chans[4] = {256, 64, 16, 4};
    const int couts[4] = {64, 16, 4, 1};

    const long long A_OFF  = 256;
    const long long A_SLOT = 1048576;   // floats
    const long long B_SLOT = 4194304;   // floats: c_j * (128<<j)^2, same all stages

    bool par = ws_size >= (size_t)(A_OFF + 4 * A_SLOT + 4 * B_SLOT) * 4;
    int nA = par ? 4 : 1;
    float* accs = ws;
    float* bufA = ws + A_OFF;
    float* bufB = ws + A_OFF + nA * A_SLOT;

    // mask = -100 everywhere
    fill_kernel<<<(4194304 + 255) / 256, 256, 0, stream>>>(out, 4194304, -100.0f);

    if (par) {
        for (int j = 0; j < 4; j++) {
            int c = chans[j], co = couts[j], shift = j;
            int inPitch = 64 << j;
            long long inPlane = (long long)inPitch * inPitch;
            int upPitch = 128 << j;
            int tiles = upPitch / 16;
            int E = 128 << j;
            long long emStride = (long long)c * E * E;

            const float* gin = (j == 0) ? x : bufA;
            long long ginStride = (j == 0) ? (long long)256 * 64 * 64 : A_SLOT;
            int useOrig = (j == 0) ? 1 : 0;

            zero8_kernel<<<1, 64, 0, stream>>>(accs);
            gn_reduce_kernel<<<dim3(512, 1, 4), 256, 0, stream>>>(
                gin, ginStride, inPitch, inPlane, useOrig, c, shift, bboxes, 0, accs);
            normup_kernel<<<dim3(tiles, tiles * c, 4), dim3(16, 16), 0, stream>>>(
                gin, ginStride, inPitch, inPlane, useOrig,
                em[j], emStride, E, gw[j], gb[j], accs,
                bufB, B_SLOT, upPitch, c, shift, bboxes, 0, tiles);
            launch_conv(co, tiles, 4,
                        bufB, B_SLOT, upPitch, cw[j], cb[j], c, (j < 3) ? 1 : 0,
                        (j < 3) ? bufA : out, (j < 3) ? A_SLOT : 0, upPitch,
                        (j == 3) ? 1 : 0, shift, bboxes, 0, stream);
        }
    } else {
        for (int i = 0; i < 4; i++) {
            for (int j = 0; j < 4; j++) {
                int c = chans[j], co = couts[j], shift = j;
                int inPitch = 64 << j;
                long long inPlane = (long long)inPitch * inPitch;
                int upPitch = 128 << j;
                int tiles = upPitch / 16;
                int E = 128 << j;
                long long emStride = (long long)c * E * E;

                const float* gin = (j == 0) ? (x + (long long)i * 256 * 64 * 64) : bufA;
                int useOrig = (j == 0) ? 1 : 0;

                zero8_kernel<<<1, 64, 0, stream>>>(accs);
                gn_reduce_kernel<<<dim3(512, 1, 1), 256, 0, stream>>>(
                    gin, 0, inPitch, inPlane, useOrig, c, shift, bboxes, i, accs);
                normup_kernel<<<dim3(tiles, tiles * c, 1), dim3(16, 16), 0, stream>>>(
                    gin, 0, inPitch, inPlane, useOrig,
                    em[j] + (long long)i * emStride, 0, E, gw[j], gb[j], accs,
                    bufB, 0, upPitch, c, shift, bboxes, i, tiles);
                launch_conv(co, tiles, 1,
                            bufB, 0, upPitch, cw[j], cb[j], c, (j < 3) ? 1 : 0,
                            (j < 3) ? bufA : out, 0, upPitch,
                            (j == 3) ? 1 : 0, shift, bboxes, i, stream);
            }
        }
    }
}

// Round 12
// 1754.963 us; speedup vs baseline: 1.6369x; 1.6369x over previous
//
#include <hip/hip_runtime.h>

#define EPS 1e-5f

// ---------------------------------------------------------------------------
// fill output mask with -100
// ---------------------------------------------------------------------------
__global__ void fill_kernel(float* __restrict__ out, int n, float v) {
    int i = blockIdx.x * blockDim.x + threadIdx.x;
    if (i < n) out[i] = v;
}

__global__ void zero8_kernel(float* __restrict__ a) {
    if (threadIdx.x < 8) a[threadIdx.x] = 0.f;
}

// ---------------------------------------------------------------------------
// GroupNorm(1) reduction: sum & sumsq over the (c, h, w) crop -> accs[2*batch]
// ---------------------------------------------------------------------------
__global__ void gn_reduce_kernel(const float* __restrict__ in, long long inBatchStride,
                                 int inPitch, long long inPlane, int useOrig,
                                 int c, int shift, const int* __restrict__ bboxes,
                                 int batch0, float* __restrict__ accs)
{
    int batch = batch0 + blockIdx.z;
    const int* bb = bboxes + 4 * batch;
    int l = bb[0], t = bb[1], r = bb[2], btm = bb[3];
    int h = (btm - t) << shift;
    int w = (r   - l) << shift;
    int oy = useOrig ? t : 0;   // only used at stage 0 (shift==0)
    int ox = useOrig ? l : 0;
    const float* base = in + (long long)blockIdx.z * inBatchStride;

    float s = 0.f, s2 = 0.f;
    int stride = gridDim.x * blockDim.x;

    if (((w | ox | inPitch) & 3) == 0) {
        // vectorized: every row segment is 16B aligned
        int w4 = w >> 2;
        int count4 = c * h * w4;
        for (int idx = blockIdx.x * blockDim.x + threadIdx.x; idx < count4; idx += stride) {
            int xw   = idx % w4;
            int rest = idx / w4;
            int y    = rest % h;
            int ch   = rest / h;
            const float4 v = *reinterpret_cast<const float4*>(
                base + (long long)ch * inPlane + (long long)(y + oy) * inPitch + (ox + 4 * xw));
            s  += (v.x + v.y) + (v.z + v.w);
            s2 += (v.x * v.x + v.y * v.y) + (v.z * v.z + v.w * v.w);
        }
    } else {
        int count = c * h * w;
        for (int idx = blockIdx.x * blockDim.x + threadIdx.x; idx < count; idx += stride) {
            int xw   = idx % w;
            int rest = idx / w;
            int y    = rest % h;
            int ch   = rest / h;
            float v = base[(long long)ch * inPlane + (long long)(y + oy) * inPitch + (xw + ox)];
            s  += v;
            s2 += v * v;
        }
    }

    // wave64 reduction
    for (int off = 32; off > 0; off >>= 1) {
        s  += __shfl_down(s, off);
        s2 += __shfl_down(s2, off);
    }
    // block reduction (4 waves) -> single atomic pair
    __shared__ float red[2][4];
    int wid = threadIdx.x >> 6;
    if ((threadIdx.x & 63) == 0) { red[0][wid] = s; red[1][wid] = s2; }
    __syncthreads();
    if (threadIdx.x == 0) {
        float ts = (red[0][0] + red[0][1]) + (red[0][2] + red[0][3]);
        float t2 = (red[1][0] + red[1][1]) + (red[1][2] + red[1][3]);
        atomicAdd(&accs[2 * batch],     ts);
        atomicAdd(&accs[2 * batch + 1], t2);
    }
}

// ---------------------------------------------------------------------------
// normalize (affine folded) + bicubic 2x (both axes, 16 taps) + add em crop
// writes bufB (c, 2h, 2w) with pitch outPitch
// ---------------------------------------------------------------------------
__global__ void normup_kernel(const float* __restrict__ in, long long inBatchStride,
                              int inPitch, long long inPlane, int useOrig,
                              const float* __restrict__ em, long long emBatchStride, int emPitch,
                              const float* __restrict__ gw, const float* __restrict__ gb,
                              const float* __restrict__ accs,
                              float* __restrict__ outB, long long outBatchStride, int outPitch,
                              int c, int shift, const int* __restrict__ bboxes,
                              int batch0, int tilesY)
{
    int batch = batch0 + blockIdx.z;
    const int* bb = bboxes + 4 * batch;
    int l = bb[0], t = bb[1], r = bb[2], btm = bb[3];
    int h = (btm - t) << shift;
    int w = (r   - l) << shift;
    int H2 = 2 * h, W2 = 2 * w;

    int ch = blockIdx.y / tilesY;
    int ty = blockIdx.y % tilesY;
    int y2 = ty * 16 + threadIdx.y;
    int x2 = blockIdx.x * 16 + threadIdx.x;
    if (y2 >= H2 || x2 >= W2) return;

    float count = (float)(c * h * w);
    float m  = accs[2 * batch] / count;
    float var = accs[2 * batch + 1] / count - m * m;
    float rs = rsqrtf(fmaxf(var, 0.f) + EPS);
    float alpha = rs * gw[ch];
    float beta  = gb[ch] - m * alpha;

    int oy = useOrig ? t : 0;
    int ox = useOrig ? l : 0;
    const float* base = in + (long long)blockIdx.z * inBatchStride + (long long)ch * inPlane;

    const float Wv[2][4] = {
        {-0.03515625f, 0.26171875f, 0.87890625f, -0.10546875f},   // even (W75)
        {-0.10546875f, 0.87890625f, 0.26171875f, -0.03515625f}};  // odd  (W25)

    int iy = y2 >> 1, py = y2 & 1;
    int ix = x2 >> 1, px = x2 & 1;
    int by = iy - 2 + py;
    int bx = ix - 2 + px;

    float acc = 0.f;
    #pragma unroll
    for (int a = 0; a < 4; a++) {
        int ry = by + a;
        ry = ry < 0 ? 0 : (ry > h - 1 ? h - 1 : ry);
        const float* rowp = base + (long long)(ry + oy) * inPitch + ox;
        float rsum = 0.f;
        #pragma unroll
        for (int q = 0; q < 4; q++) {
            int rx = bx + q;
            rx = rx < 0 ? 0 : (rx > w - 1 ? w - 1 : rx);
            rsum += Wv[px][q] * rowp[rx];
        }
        acc += Wv[py][a] * rsum;
    }

    float val = alpha * acc + beta;
    int S = 2 << shift;  // 2^(j+1)
    val += em[(long long)blockIdx.z * emBatchStride + (long long)ch * emPitch * emPitch
              + (long long)(t * S + y2) * emPitch + (l * S + x2)];

    outB[(long long)blockIdx.z * outBatchStride + (long long)ch * outPitch * outPitch
         + (long long)y2 * outPitch + x2] = val;
}

// ---------------------------------------------------------------------------
// conv3x3 (zero pad) + bias (+ silu).
// Block = 16x16 threads, each owning a 2x2 output patch -> 32x32 tile.
// Input staged in LDS in CICH-plane chunks (34x34 halo, row stride 36).
// Weights staged in LDS per chunk; each (plane, oc) weight read (2x float4 +
// 1 float, broadcast) feeds 36 FMAs (2x2 pixels x 9 taps) -> 12:1
// FMA:LDS-read ratio, vs 4.5:1 in the R5 version which was
// LDS-issue-bound (R5: 1701 us, VALUBusy 15.9%, occupancy 6.5%).
// COT=8 keeps acc at 32 VGPRs to recover occupancy (R5 hit 144 VGPRs).
// ---------------------------------------------------------------------------
#define CICH 4

template<int COT>
__global__ void __launch_bounds__(256)
conv_reg_kernel(const float* __restrict__ inB, long long inBatchStride, int inPitch,
                const float* __restrict__ wts, const float* __restrict__ bias,
                int cin, int doSilu,
                float* __restrict__ out, long long outBatchStride, int outPitch,
                int toMask, int shift, const int* __restrict__ bboxes,
                int batch0, int tilesY)
{
    int batch = batch0 + blockIdx.z;
    const int* bb = bboxes + 4 * batch;
    int l = bb[0], t = bb[1], r = bb[2], btm = bb[3];
    int h = (btm - t) << shift;
    int w = (r   - l) << shift;
    int H2 = 2 * h, W2 = 2 * w;

    int og = blockIdx.y / tilesY;
    int ty = blockIdx.y % tilesY;
    int oc0 = og * COT;
    int y0 = ty * 32;
    int x0 = blockIdx.x * 32;
    if (y0 >= H2 || x0 >= W2) return;  // uniform over block

    int ly = threadIdx.y, lx = threadIdx.x;
    int tid = ly * 16 + lx;
    int py0 = y0 + 2 * ly;   // this thread's 2x2 output base
    int px0 = x0 + 2 * lx;

    // 34x34 halo tile, row stride 36 (keeps float2 reads 8B-aligned)
    __shared__ float tile[CICH][34][36];
    // per-chunk weights; slot padded to 12 floats -> two aligned float4 + one
    __shared__ __align__(16) float wsh[COT][CICH][12];

    const float* base = inB + (long long)blockIdx.z * inBatchStride;
    long long plane = (long long)inPitch * inPitch;

    float acc[COT][2][2];
    #pragma unroll
    for (int o = 0; o < COT; o++)
        #pragma unroll
        for (int rr = 0; rr < 2; rr++)
            #pragma unroll
            for (int ss = 0; ss < 2; ss++) acc[o][rr][ss] = 0.f;

    for (int ci0 = 0; ci0 < cin; ci0 += CICH) {
        // stage CICH input planes (34x34 halo each) into LDS
        for (int q = tid; q < CICH * 1156; q += 256) {
            int p   = q / 1156;
            int rem = q - p * 1156;
            int yy  = rem / 34;
            int xx  = rem - yy * 34;
            int gy = y0 - 1 + yy, gx = x0 - 1 + xx;
            float v = (gy >= 0 && gy < H2 && gx >= 0 && gx < W2)
                          ? base[(long long)(ci0 + p) * plane + (long long)gy * inPitch + gx]
                          : 0.f;
            tile[p][yy][xx] = v;
        }
        // stage this chunk's weights (COT*CICH*9 <= 288 floats, coalesced)
        for (int q = tid; q < COT * CICH * 9; q += 256) {
            int o   = q / (CICH * 9);
            int rem = q - o * (CICH * 9);
            int p   = rem / 9;
            int k   = rem - p * 9;
            wsh[o][p][k] = wts[((long long)(oc0 + o) * cin + (ci0 + p)) * 9 + k];
        }
        __syncthreads();

        #pragma unroll
        for (int p = 0; p < CICH; p++) {
            // 4x4 input patch for this thread's 2x2 outputs (8x ds_read_b64)
            float v[4][4];
            #pragma unroll
            for (int rr = 0; rr < 4; rr++) {
                const float2 a = *reinterpret_cast<const float2*>(&tile[p][2 * ly + rr][2 * lx]);
                const float2 b = *reinterpret_cast<const float2*>(&tile[p][2 * ly + rr][2 * lx + 2]);
                v[rr][0] = a.x; v[rr][1] = a.y; v[rr][2] = b.x; v[rr][3] = b.y;
            }
            #pragma unroll
            for (int o = 0; o < COT; o++) {
                const float4 wA = *reinterpret_cast<const float4*>(&wsh[o][p][0]);
                const float4 wB = *reinterpret_cast<const float4*>(&wsh[o][p][4]);
                const float  w8 = wsh[o][p][8];
                #pragma unroll
                for (int rr = 0; rr < 2; rr++) {
                    #pragma unroll
                    for (int ss = 0; ss < 2; ss++) {
                        acc[o][rr][ss] += wA.x * v[rr    ][ss] + wA.y * v[rr    ][ss + 1] + wA.z * v[rr    ][ss + 2]
                                        + wA.w * v[rr + 1][ss] + wB.x * v[rr + 1][ss + 1] + wB.y * v[rr + 1][ss + 2]
                                        + wB.z * v[rr + 2][ss] + wB.w * v[rr + 2][ss + 1] + w8   * v[rr + 2][ss + 2];
                    }
                }
            }
        }
        __syncthreads();
    }

    #pragma unroll
    for (int o = 0; o < COT; o++) {
        float b = bias[oc0 + o];
        #pragma unroll
        for (int rr = 0; rr < 2; rr++) {
            #pragma unroll
            for (int ss = 0; ss < 2; ss++) {
                int oy2 = py0 + rr, ox2 = px0 + ss;
                if (oy2 >= H2 || ox2 >= W2) continue;
                float v = acc[o][rr][ss] + b;
                if (doSilu) v = v / (1.f + __expf(-v));
                if (toMask) {
                    int S = 2 << shift;   // 16 at stage 3
                    out[(long long)batch * 1024 * 1024 + (long long)(t * S + oy2) * 1024 + (l * S + ox2)] = v;
                } else {
                    out[(long long)blockIdx.z * outBatchStride + (long long)(oc0 + o) * outPitch * outPitch
                        + (long long)oy2 * outPitch + ox2] = v;
                }
            }
        }
    }
}

// ---------------------------------------------------------------------------
static inline void launch_conv(int co, int tiles32, int nz, const float* inB, long long inBS, int inPitch,
                               const float* wts, const float* bias, int cin, int doSilu,
                               float* out, long long outBS, int outPitch,
                               int toMask, int shift, const int* bboxes, int batch0,
                               hipStream_t stream)
{
    dim3 blk(16, 16);
    if (co == 64) {       // 8 groups of 8
        conv_reg_kernel<8><<<dim3(tiles32, tiles32 * 8, nz), blk, 0, stream>>>(
            inB, inBS, inPitch, wts, bias, cin, doSilu, out, outBS, outPitch,
            toMask, shift, bboxes, batch0, tiles32);
    } else if (co == 16) {  // 2 groups of 8
        conv_reg_kernel<8><<<dim3(tiles32, tiles32 * 2, nz), blk, 0, stream>>>(
            inB, inBS, inPitch, wts, bias, cin, doSilu, out, outBS, outPitch,
            toMask, shift, bboxes, batch0, tiles32);
    } else if (co == 4) {
        conv_reg_kernel<4><<<dim3(tiles32, tiles32, nz), blk, 0, stream>>>(
            inB, inBS, inPitch, wts, bias, cin, doSilu, out, outBS, outPitch,
            toMask, shift, bboxes, batch0, tiles32);
    } else {
        conv_reg_kernel<1><<<dim3(tiles32, tiles32, nz), blk, 0, stream>>>(
            inB, inBS, inPitch, wts, bias, cin, doSilu, out, outBS, outPitch,
            toMask, shift, bboxes, batch0, tiles32);
    }
}

extern "C" void kernel_launch(void* const* d_in, const int* in_sizes, int n_in,
                              void* d_out, int out_size, void* d_ws, size_t ws_size,
                              hipStream_t stream)
{
    const float* x  = (const float*)d_in[0];
    const float* em[4];
    const float* gw[4];
    const float* gb[4];
    const float* cw[4];
    const float* cb[4];
    for (int j = 0; j < 4; j++) {
        em[j] = (const float*)d_in[1 + j];
        gw[j] = (const float*)d_in[5 + 4 * j];
        gb[j] = (const float*)d_in[6 + 4 * j];
        cw[j] = (const float*)d_in[7 + 4 * j];
        cb[j] = (const float*)d_in[8 + 4 * j];
    }
    const int* bboxes = (const int*)d_in[21];
    float* out = (float*)d_out;
    float* ws  = (float*)d_ws;

    const int chans[4] = {256, 64, 16, 4};
    const int couts[4] = {64, 16, 4, 1};

    const long long A_OFF  = 256;
    const long long A_SLOT = 1048576;   // floats
    const long long B_SLOT = 4194304;   // floats: c_j * (128<<j)^2, same all stages

    bool par = ws_size >= (size_t)(A_OFF + 4 * A_SLOT + 4 * B_SLOT) * 4;
    int nA = par ? 4 : 1;
    float* accs = ws;
    float* bufA = ws + A_OFF;
    float* bufB = ws + A_OFF + nA * A_SLOT;

    // mask = -100 everywhere
    fill_kernel<<<(4194304 + 255) / 256, 256, 0, stream>>>(out, 4194304, -100.0f);

    if (par) {
        for (int j = 0; j < 4; j++) {
            int c = chans[j], co = couts[j], shift = j;
            int inPitch = 64 << j;
            long long inPlane = (long long)inPitch * inPitch;
            int upPitch = 128 << j;
            int tiles = upPitch / 16;
            int tiles32 = upPitch / 32;
            int E = 128 << j;
            long long emStride = (long long)c * E * E;

            const float* gin = (j == 0) ? x : bufA;
            long long ginStride = (j == 0) ? (long long)256 * 64 * 64 : A_SLOT;
            int useOrig = (j == 0) ? 1 : 0;

            zero8_kernel<<<1, 64, 0, stream>>>(accs);
            gn_reduce_kernel<<<dim3(512, 1, 4), 256, 0, stream>>>(
                gin, ginStride, inPitch, inPlane, useOrig, c, shift, bboxes, 0, accs);
            normup_kernel<<<dim3(tiles, tiles * c, 4), dim3(16, 16), 0, stream>>>(
                gin, ginStride, inPitch, inPlane, useOrig,
                em[j], emStride, E, gw[j], gb[j], accs,
                bufB, B_SLOT, upPitch, c, shift, bboxes, 0, tiles);
            launch_conv(co, tiles32, 4,
                        bufB, B_SLOT, upPitch, cw[j], cb[j], c, (j < 3) ? 1 : 0,
                        (j < 3) ? bufA : out, (j < 3) ? A_SLOT : 0, upPitch,
                        (j == 3) ? 1 : 0, shift, bboxes, 0, stream);
        }
    } else {
        for (int i = 0; i < 4; i++) {
            for (int j = 0; j < 4; j++) {
                int c = chans[j], co = couts[j], shift = j;
                int inPitch = 64 << j;
                long long inPlane = (long long)inPitch * inPitch;
                int upPitch = 128 << j;
                int tiles = upPitch / 16;
                int tiles32 = upPitch / 32;
                int E = 128 << j;
                long long emStride = (long long)c * E * E;

                const float* gin = (j == 0) ? (x + (long long)i * 256 * 64 * 64) : bufA;
                int useOrig = (j == 0) ? 1 : 0;

                zero8_kernel<<<1, 64, 0, stream>>>(accs);
                gn_reduce_kernel<<<dim3(512, 1, 1), 256, 0, stream>>>(
                    gin, 0, inPitch, inPlane, useOrig, c, shift, bboxes, i, accs);
                normup_kernel<<<dim3(tiles, tiles * c, 1), dim3(16, 16), 0, stream>>>(
                    gin, 0, inPitch, inPlane, useOrig,
                    em[j] + (long long)i * emStride, 0, E, gw[j], gb[j], accs,
                    bufB, 0, upPitch, c, shift, bboxes, i, tiles);
                launch_conv(co, tiles32, 1,
                            bufB, 0, upPitch, cw[j], cb[j], c, (j < 3) ? 1 : 0,
                            (j < 3) ? bufA : out, 0, upPitch,
                            (j == 3) ? 1 : 0, shift, bboxes, i, stream);
            }
        }
    }
}